// Round 1
// baseline (42.914 us; speedup 1.0000x reference)
//
#include <hip/hip_runtime.h>
#include <math.h>

#define BATCH 32
#define NPTS 131072
#define NVEC (NPTS / 4)          // float4 chunks per row = 32768 = 2^15
#define NVEC_SHIFT 15

// d_ws layout (floats):
//   ws[0]            = point-cloud err accumulator (zeroed by prep each call)
//   ws[1]            = loss_rot
//   ws[4 + b*12 + k] = D[b] = (R_p^T R_t - I), row-major 3x3 (k=0..8), padded to 12

__global__ void prep_kernel(const float* __restrict__ t_rot,
                            const float* __restrict__ r_err,
                            float* __restrict__ ws)
{
    __shared__ float qd[BATCH];
    const int b = threadIdx.x;
    if (b == 0) ws[0] = 0.0f;
    if (b < BATCH) {
        float tw = t_rot[b*4+0], tx = t_rot[b*4+1], ty = t_rot[b*4+2], tz = t_rot[b*4+3];
        float pw = r_err[b*4+0], px = r_err[b*4+1], py = r_err[b*4+2], pz = r_err[b*4+3];

        // quaternion_distance(rot_err, target_rot) on RAW quats (scale-invariant)
        {
            float r0 = tw, r1 = -tx, r2 = -ty, r3 = -tz;
            float q0 = pw, q1 = px, q2 = py, q3 = pz;
            float u0 = r0*q0 - r1*q1 - r2*q2 - r3*q3;
            float u1 = r0*q1 + r1*q0 - r2*q3 + r3*q2;
            float u2 = r0*q2 + r1*q3 + r2*q0 - r3*q1;
            float u3 = r0*q3 - r1*q2 + r2*q1 + r3*q0;
            float vn = sqrtf(u1*u1 + u2*u2 + u3*u3);
            qd[b] = 2.0f * atan2f(vn, fabsf(u0));
        }

        // normalize quats, build rotation matrices
        float ni = rsqrtf(tw*tw + tx*tx + ty*ty + tz*tz);
        tw *= ni; tx *= ni; ty *= ni; tz *= ni;
        ni = rsqrtf(pw*pw + px*px + py*py + pz*pz);
        pw *= ni; px *= ni; py *= ni; pz *= ni;

        float Rt[3][3], Rp[3][3];
        Rt[0][0] = 1.f - 2.f*(ty*ty + tz*tz); Rt[0][1] = 2.f*(tx*ty - tz*tw);       Rt[0][2] = 2.f*(tx*tz + ty*tw);
        Rt[1][0] = 2.f*(tx*ty + tz*tw);       Rt[1][1] = 1.f - 2.f*(tx*tx + tz*tz); Rt[1][2] = 2.f*(ty*tz - tx*tw);
        Rt[2][0] = 2.f*(tx*tz - ty*tw);       Rt[2][1] = 2.f*(ty*tz + tx*tw);       Rt[2][2] = 1.f - 2.f*(tx*tx + ty*ty);

        Rp[0][0] = 1.f - 2.f*(py*py + pz*pz); Rp[0][1] = 2.f*(px*py - pz*pw);       Rp[0][2] = 2.f*(px*pz + py*pw);
        Rp[1][0] = 2.f*(px*py + pz*pw);       Rp[1][1] = 1.f - 2.f*(px*px + pz*pz); Rp[1][2] = 2.f*(py*pz - px*pw);
        Rp[2][0] = 2.f*(px*pz - py*pw);       Rp[2][1] = 2.f*(py*pz + px*pw);       Rp[2][2] = 1.f - 2.f*(px*px + py*py);

        // A = Rp^T * Rt ; store D = A - I
        float* D = ws + 4 + b*12;
        #pragma unroll
        for (int i = 0; i < 3; ++i) {
            #pragma unroll
            for (int j = 0; j < 3; ++j) {
                float a = Rp[0][i]*Rt[0][j] + Rp[1][i]*Rt[1][j] + Rp[2][i]*Rt[2][j];
                D[i*3 + j] = a - ((i == j) ? 1.0f : 0.0f);
            }
        }
    }
    __syncthreads();
    if (b == 0) {
        float s = 0.0f;
        #pragma unroll
        for (int i = 0; i < BATCH; ++i) s += qd[i];
        ws[1] = s / (float)BATCH;   // loss_rot
    }
}

__global__ __launch_bounds__(256) void pc_kernel(const float* __restrict__ pc,
                                                 const float* __restrict__ ws)
{
    const int tid    = blockIdx.x * blockDim.x + threadIdx.x;
    const int stride = gridDim.x * blockDim.x;
    const int total  = BATCH * NVEC;
    const float* mats = ws + 4;

    float sum = 0.0f;
    for (int idx = tid; idx < total; idx += stride) {
        const int b = idx >> NVEC_SHIFT;
        const int c = idx & (NVEC - 1);
        const float* base = pc + (size_t)b * 4 * NPTS;
        float4 X = ((const float4*)(base          ))[c];
        float4 Y = ((const float4*)(base +     NPTS))[c];
        float4 Z = ((const float4*)(base + 2 * NPTS))[c];
        const float* D = mats + b * 12;
        const float d00 = D[0], d01 = D[1], d02 = D[2];
        const float d10 = D[3], d11 = D[4], d12 = D[5];
        const float d20 = D[6], d21 = D[7], d22 = D[8];

        float e0, e1, e2;
        e0 = d00*X.x + d01*Y.x + d02*Z.x;
        e1 = d10*X.x + d11*Y.x + d12*Z.x;
        e2 = d20*X.x + d21*Y.x + d22*Z.x;
        sum += sqrtf(e0*e0 + e1*e1 + e2*e2);

        e0 = d00*X.y + d01*Y.y + d02*Z.y;
        e1 = d10*X.y + d11*Y.y + d12*Z.y;
        e2 = d20*X.y + d21*Y.y + d22*Z.y;
        sum += sqrtf(e0*e0 + e1*e1 + e2*e2);

        e0 = d00*X.z + d01*Y.z + d02*Z.z;
        e1 = d10*X.z + d11*Y.z + d12*Z.z;
        e2 = d20*X.z + d21*Y.z + d22*Z.z;
        sum += sqrtf(e0*e0 + e1*e1 + e2*e2);

        e0 = d00*X.w + d01*Y.w + d02*Z.w;
        e1 = d10*X.w + d11*Y.w + d12*Z.w;
        e2 = d20*X.w + d21*Y.w + d22*Z.w;
        sum += sqrtf(e0*e0 + e1*e1 + e2*e2);
    }

    // wave64 reduce
    #pragma unroll
    for (int off = 32; off > 0; off >>= 1)
        sum += __shfl_down(sum, off, 64);

    __shared__ float wsum[4];
    const int lane = threadIdx.x & 63;
    const int wave = threadIdx.x >> 6;
    if (lane == 0) wsum[wave] = sum;
    __syncthreads();
    if (threadIdx.x == 0) {
        float bsum = wsum[0] + wsum[1] + wsum[2] + wsum[3];
        atomicAdd((float*)ws, bsum);
    }
}

__global__ void finish_kernel(const float* __restrict__ ws, float* __restrict__ out)
{
    if (threadIdx.x == 0 && blockIdx.x == 0) {
        const float pc_sum   = ws[0];
        const float loss_rot = ws[1];
        const float pcB = pc_sum / (float)NPTS / (float)BATCH;   // point_clouds_loss / B
        out[0] = 0.5f * loss_rot + 0.5f * pcB;                   // total_loss
        out[1] = loss_rot;
        out[2] = pcB;
    }
}

extern "C" void kernel_launch(void* const* d_in, const int* in_sizes, int n_in,
                              void* d_out, int out_size, void* d_ws, size_t ws_size,
                              hipStream_t stream)
{
    const float* pc      = (const float*)d_in[0];  // [32, 4, 131072]
    // d_in[1] = target_transl — cancels analytically, unused
    const float* t_rot   = (const float*)d_in[2];  // [32, 4]
    const float* r_err   = (const float*)d_in[3];  // [32, 4]
    float* out = (float*)d_out;
    float* ws  = (float*)d_ws;

    prep_kernel<<<1, 64, 0, stream>>>(t_rot, r_err, ws);
    pc_kernel<<<2048, 256, 0, stream>>>(pc, ws);
    finish_kernel<<<1, 64, 0, stream>>>(ws, out);
}